// Round 7
// baseline (179.570 us; speedup 1.0000x reference)
//
#include <hip/hip_runtime.h>

#define ED 1024      // EMBED_DIM
#define AD 256       // ATTN_DIM
#define BB 16        // batch
#define NK 4096      // keys
#define RPB 16       // rows per block in the streaming kernels
#define NBLK (BB * NK / RPB)   // 4096 streaming blocks

// ws layout (floats):
#define OFF_QP    0           // BB*AD            = 4096
#define OFF_T     4096        // BB*ED            = 16384
#define OFF_W     20480       // BB*NK            = 65536
#define OFF_WSP   86016       // NBLK             = 4096
#define OFF_PART  90112       // NBLK*ED          = 4194304 (16 MB)
#define OFF_PART2 4284416     // 16*BB*ED         = 262144
#define OFF_OV    4546560     // BB*ED            = 16384
#define OFF_OPART 4562944     // 4*BB*ED          = 65536
// total ~4.63M floats (~18.5 MB) << ws

// ---------------------------------------------------------------------------
// Kernel 1: qp[b,c] = bkq[c] + sum_d q[b,d]*Wkq[d,c].  grid (16,4), block 256.
__global__ void k_qp(const float* __restrict__ q, const float* __restrict__ Wkq,
                     const float* __restrict__ bkq, float* __restrict__ qp) {
    int b = blockIdx.x, cg = blockIdx.y, tid = threadIdx.x;
    int c = cg * 64 + (tid & 63), dg = tid >> 6;
    __shared__ float qsh[ED];
    ((float4*)qsh)[tid] = ((const float4*)(q + b * ED))[tid];
    __syncthreads();
    float acc = 0.f;
    #pragma unroll 8
    for (int d = dg; d < ED; d += 4) acc += qsh[d] * Wkq[(size_t)d * AD + c];
    __shared__ float red[4][64];
    red[dg][tid & 63] = acc;
    __syncthreads();
    if (tid < 64) {
        float s = red[0][tid] + red[1][tid] + red[2][tid] + red[3][tid];
        qp[b * AD + cg * 64 + tid] = s + bkq[cg * 64 + tid];
    }
}

// Kernel 2: t[b,d] = Wkq[d,:].qp[b,:]. grid (8,16), block 256, 2-row ILP.
__global__ void k_t(const float* __restrict__ Wkq, const float* __restrict__ qp,
                    float* __restrict__ t) {
    int b = blockIdx.y, dbase = blockIdx.x * 128;
    int tid = threadIdx.x, wave = tid >> 6, lane = tid & 63;
    float4 qv = ((const float4*)(qp + b * AD))[lane];
    for (int r = 0; r < 16; ++r) {
        int d1 = dbase + wave * 32 + r;
        int d2 = d1 + 16;
        float4 w1 = ((const float4*)(Wkq + (size_t)d1 * AD))[lane];
        float4 w2 = ((const float4*)(Wkq + (size_t)d2 * AD))[lane];
        float s1 = w1.x*qv.x + w1.y*qv.y + w1.z*qv.z + w1.w*qv.w;
        float s2 = w2.x*qv.x + w2.y*qv.y + w2.z*qv.z + w2.w*qv.w;
        #pragma unroll
        for (int off = 32; off; off >>= 1) {
            s1 += __shfl_down(s1, off, 64);
            s2 += __shfl_down(s2, off, 64);
        }
        if (lane == 0) { t[b * ED + d1] = s1; t[b * ED + d2] = s2; }
    }
}

// Kernel 3: k-stream. Block = 16 consecutive k-rows (64 KB), dispatch-linear.
// wave handles 4 rows (2 passes x 2-row ILP). w = exp(k.t/16) -> global;
// per-block weight sum -> wsumPart. grid NBLK=4096, block 256.
__global__ __launch_bounds__(256, 4)
void k_scores(const float* __restrict__ k, const float* __restrict__ t,
              float* __restrict__ w, float* __restrict__ wsumPart) {
    int bid = blockIdx.x;
    int b = bid >> 8, ch = bid & 255;          // 256 chunks per batch
    int tid = threadIdx.x, wave = tid >> 6, lane = tid & 63;
    const float4* tb = (const float4*)(t + b * ED);
    float4 t0 = tb[lane], t1 = tb[64 + lane], t2 = tb[128 + lane], t3 = tb[192 + lane];
    int row0 = ch * RPB + wave * 4;
    __shared__ float wsh[RPB];
    #pragma unroll
    for (int pr = 0; pr < 2; ++pr) {
        int rA = row0 + pr * 2, rB = rA + 1;
        const float4* ka = (const float4*)(k + ((size_t)b * NK + rA) * ED);
        const float4* kb = (const float4*)(k + ((size_t)b * NK + rB) * ED);
        float4 a0 = ka[lane], a1 = ka[64 + lane], a2 = ka[128 + lane], a3 = ka[192 + lane];
        float4 c0 = kb[lane], c1 = kb[64 + lane], c2 = kb[128 + lane], c3 = kb[192 + lane];
        float sA = a0.x*t0.x + a0.y*t0.y + a0.z*t0.z + a0.w*t0.w
                 + a1.x*t1.x + a1.y*t1.y + a1.z*t1.z + a1.w*t1.w
                 + a2.x*t2.x + a2.y*t2.y + a2.z*t2.z + a2.w*t2.w
                 + a3.x*t3.x + a3.y*t3.y + a3.z*t3.z + a3.w*t3.w;
        float sB = c0.x*t0.x + c0.y*t0.y + c0.z*t0.z + c0.w*t0.w
                 + c1.x*t1.x + c1.y*t1.y + c1.z*t1.z + c1.w*t1.w
                 + c2.x*t2.x + c2.y*t2.y + c2.z*t2.z + c2.w*t2.w
                 + c3.x*t3.x + c3.y*t3.y + c3.z*t3.z + c3.w*t3.w;
        #pragma unroll
        for (int m = 32; m; m >>= 1) {
            sA += __shfl_xor(sA, m, 64);
            sB += __shfl_xor(sB, m, 64);
        }
        if (lane == 0) {
            float wA = __expf(sA * 0.0625f), wB = __expf(sB * 0.0625f);
            w[b * NK + rA] = wA;
            w[b * NK + rB] = wB;
            wsh[wave * 4 + pr * 2]     = wA;
            wsh[wave * 4 + pr * 2 + 1] = wB;
        }
    }
    __syncthreads();
    if (wave == 0) {
        float s = (lane < RPB) ? wsh[lane] : 0.f;
        s += __shfl_xor(s, 8, 64);
        s += __shfl_xor(s, 4, 64);
        s += __shfl_xor(s, 2, 64);
        s += __shfl_xor(s, 1, 64);
        if (lane == 0) wsumPart[bid] = s;
    }
}

// Kernel 4: v-stream (copy-shaped). Block = 16 consecutive v-rows; thread =
// fixed float4 column; 16 fully-unrolled independent loads, acc-only chain.
// partial[bid][tid] = sum_r w[r]*v4[r][tid]. grid NBLK=4096, block 256.
__global__ __launch_bounds__(256, 4)
void k_pv(const float* __restrict__ v, const float* __restrict__ w,
          float* __restrict__ partial) {
    int bid = blockIdx.x;
    int b = bid >> 8, ch = bid & 255;
    int tid = threadIdx.x;
    __shared__ float wsh[RPB];
    if (tid < RPB) wsh[tid] = w[b * NK + ch * RPB + tid];
    __syncthreads();
    const float4* vb = (const float4*)(v + ((size_t)b * NK + (size_t)ch * RPB) * ED);
    float4 acc = {0.f, 0.f, 0.f, 0.f};
    #pragma unroll
    for (int r = 0; r < RPB; ++r) {
        float wt = wsh[r];
        float4 vv = vb[(size_t)r * (ED / 4) + tid];
        acc.x += wt * vv.x; acc.y += wt * vv.y; acc.z += wt * vv.z; acc.w += wt * vv.w;
    }
    ((float4*)partial)[(size_t)bid * (ED / 4) + tid] = acc;
}

// Kernel 5: first-level reduce: partial2[b][g][:] = sum of 16 chunk partials.
// grid (16 b, 16 g), block 256. Reads 16 MB total across 256 blocks.
__global__ void k_reduce1(const float* __restrict__ partial, float* __restrict__ partial2) {
    int b = blockIdx.x, g = blockIdx.y, tid = threadIdx.x;
    const float4* pb = (const float4*)partial + ((size_t)((b << 8) + g * 16)) * (ED / 4);
    float4 s = {0.f, 0.f, 0.f, 0.f};
    #pragma unroll
    for (int i = 0; i < 16; ++i) {
        float4 p = pb[(size_t)i * (ED / 4) + tid];
        s.x += p.x; s.y += p.y; s.z += p.z; s.w += p.w;
    }
    ((float4*)partial2)[((size_t)(b * 16 + g)) * (ED / 4) + tid] = s;
}

// Kernel 6: ov[b,:] = (sum_g partial2[b][g][:]) / wsum[b]. grid 16, block 256.
__global__ void k_reduce2(const float* __restrict__ partial2, const float* __restrict__ wsumPart,
                          float* __restrict__ ov) {
    int b = blockIdx.x, tid = threadIdx.x;
    __shared__ float red[256];
    red[tid] = wsumPart[b * 256 + tid];
    __syncthreads();
    for (int off = 128; off; off >>= 1) {
        if (tid < off) red[tid] += red[tid + off];
        __syncthreads();
    }
    float linv = 1.0f / red[0];
    float4 s = {0.f, 0.f, 0.f, 0.f};
    #pragma unroll
    for (int g = 0; g < 16; ++g) {
        float4 p = ((const float4*)partial2)[((size_t)(b * 16 + g)) * (ED / 4) + tid];
        s.x += p.x; s.y += p.y; s.z += p.z; s.w += p.w;
    }
    s.x *= linv; s.y *= linv; s.z *= linv; s.w *= linv;
    ((float4*)(ov + b * ED))[tid] = s;
}

// Kernel 7: out_part[dq][b][col] = sum_{d in quarter} ov[b,d]*Wv[d,col].
// grid (16 colblocks, 4 d-quarters), block 256 = 4 d-groups x 64 cols.
__global__ void k_out(const float* __restrict__ ov, const float* __restrict__ Wv,
                      float* __restrict__ opart) {
    int cb = blockIdx.x, dq = blockIdx.y, tid = threadIdx.x;
    int col = cb * 64 + (tid & 63), dg = tid >> 6;
    __shared__ float ovsh[BB][256];
    for (int i = tid; i < BB * 64; i += 256) {
        int bb = i >> 6, c4 = i & 63;
        ((float4*)ovsh[bb])[c4] = ((const float4*)(ov + bb * ED + dq * 256))[c4];
    }
    __syncthreads();
    float acc[BB];
    #pragma unroll
    for (int b = 0; b < BB; ++b) acc[b] = 0.f;
    #pragma unroll 8
    for (int it = 0; it < 64; ++it) {
        int dd = dg + it * 4;
        float w = Wv[(size_t)(dq * 256 + dd) * ED + col];
        #pragma unroll
        for (int b = 0; b < BB; ++b) acc[b] += ovsh[b][dd] * w;
    }
    __shared__ float red[BB][256];
    #pragma unroll
    for (int b = 0; b < BB; ++b) red[b][tid] = acc[b];
    __syncthreads();
    int bgrp = tid >> 6, c = tid & 63;
    #pragma unroll
    for (int bi = 0; bi < 4; ++bi) {
        int b = bgrp * 4 + bi;
        float s = red[b][c] + red[b][64 + c] + red[b][128 + c] + red[b][192 + c];
        opart[((size_t)(dq * BB + b)) * ED + cb * 64 + c] = s;
    }
}

// Kernel 8: out[b,:] = sum_dq out_part[dq][b][:] + bv. grid 16, block 256.
__global__ void k_final(const float* __restrict__ opart, const float* __restrict__ bv,
                        float* __restrict__ out) {
    int b = blockIdx.x, tid = threadIdx.x;
    float4 s = ((const float4*)(opart + (size_t)(0 * BB + b) * ED))[tid];
    #pragma unroll
    for (int dq = 1; dq < 4; ++dq) {
        float4 p = ((const float4*)(opart + (size_t)(dq * BB + b) * ED))[tid];
        s.x += p.x; s.y += p.y; s.z += p.z; s.w += p.w;
    }
    float4 bb = ((const float4*)bv)[tid];
    s.x += bb.x; s.y += bb.y; s.z += bb.z; s.w += bb.w;
    ((float4*)(out + b * ED))[tid] = s;
}

extern "C" void kernel_launch(void* const* d_in, const int* in_sizes, int n_in,
                              void* d_out, int out_size, void* d_ws, size_t ws_size,
                              hipStream_t stream) {
    const float* q   = (const float*)d_in[0];
    const float* k   = (const float*)d_in[1];
    const float* v   = (const float*)d_in[2];
    const float* Wkq = (const float*)d_in[3];
    const float* bkq = (const float*)d_in[4];
    const float* Wv  = (const float*)d_in[5];
    const float* bv  = (const float*)d_in[6];
    float* out = (float*)d_out;
    float* ws  = (float*)d_ws;

    float* qp      = ws + OFF_QP;
    float* t       = ws + OFF_T;
    float* w       = ws + OFF_W;
    float* wsp     = ws + OFF_WSP;
    float* partial = ws + OFF_PART;
    float* part2   = ws + OFF_PART2;
    float* ov      = ws + OFF_OV;
    float* opart   = ws + OFF_OPART;

    k_qp     <<<dim3(16, 4),  256, 0, stream>>>(q, Wkq, bkq, qp);
    k_t      <<<dim3(8, 16),  256, 0, stream>>>(Wkq, qp, t);
    k_scores <<<NBLK,         256, 0, stream>>>(k, t, w, wsp);
    k_pv     <<<NBLK,         256, 0, stream>>>(v, w, partial);
    k_reduce1<<<dim3(16, 16), 256, 0, stream>>>(partial, part2);
    k_reduce2<<<16,           256, 0, stream>>>(part2, wsp, ov);
    k_out    <<<dim3(16, 4),  256, 0, stream>>>(ov, Wv, opart);
    k_final  <<<16,           256, 0, stream>>>(opart, bv, out);
}

// Round 8
// 172.114 us; speedup vs baseline: 1.0433x; 1.0433x over previous
//
#include <hip/hip_runtime.h>

#define ED 1024      // EMBED_DIM
#define AD 256       // ATTN_DIM
#define BB 16        // batch
#define NK 4096      // keys
#define NCH 64       // v-chunks per batch
#define KCH (NK/NCH) // 64 rows per chunk

// ws layout (floats):
#define OFF_QP    0          // BB*AD       = 4096
#define OFF_T     4096       // BB*ED       = 16384
#define OFF_WSUM  20480      // BB*NCH      = 1024
#define OFF_PART  21504      // BB*NCH*ED   = 1048576
#define OFF_OV    1070080    // BB*ED       = 16384
#define OFF_OPART 1086464    // 4*BB*ED     = 65536

// ---------------------------------------------------------------------------
// Kernel 1: qp[b,c] = bkq[c] + sum_d q[b,d]*Wkq[d,c].  grid (16,4), block 256.
__global__ void k_qp(const float* __restrict__ q, const float* __restrict__ Wkq,
                     const float* __restrict__ bkq, float* __restrict__ qp) {
    int b = blockIdx.x, cg = blockIdx.y, tid = threadIdx.x;
    int c = cg * 64 + (tid & 63), dg = tid >> 6;
    __shared__ float qsh[ED];
    ((float4*)qsh)[tid] = ((const float4*)(q + b * ED))[tid];
    __syncthreads();
    float acc = 0.f;
    #pragma unroll 8
    for (int d = dg; d < ED; d += 4) acc += qsh[d] * Wkq[(size_t)d * AD + c];
    __shared__ float red[4][64];
    red[dg][tid & 63] = acc;
    __syncthreads();
    if (tid < 64) {
        float s = red[0][tid] + red[1][tid] + red[2][tid] + red[3][tid];
        qp[b * AD + cg * 64 + tid] = s + bkq[cg * 64 + tid];
    }
}

// Kernel 2: t[b,d] = Wkq[d,:].qp[b,:]. grid (8,16), block 256, 2-row ILP.
__global__ void k_t(const float* __restrict__ Wkq, const float* __restrict__ qp,
                    float* __restrict__ t) {
    int b = blockIdx.y, dbase = blockIdx.x * 128;
    int tid = threadIdx.x, wave = tid >> 6, lane = tid & 63;
    float4 qv = ((const float4*)(qp + b * AD))[lane];
    for (int r = 0; r < 16; ++r) {
        int d1 = dbase + wave * 32 + r;
        int d2 = d1 + 16;
        float4 w1 = ((const float4*)(Wkq + (size_t)d1 * AD))[lane];
        float4 w2 = ((const float4*)(Wkq + (size_t)d2 * AD))[lane];
        float s1 = w1.x*qv.x + w1.y*qv.y + w1.z*qv.z + w1.w*qv.w;
        float s2 = w2.x*qv.x + w2.y*qv.y + w2.z*qv.z + w2.w*qv.w;
        #pragma unroll
        for (int off = 32; off; off >>= 1) {
            s1 += __shfl_down(s1, off, 64);
            s2 += __shfl_down(s2, off, 64);
        }
        if (lane == 0) { t[b * ED + d1] = s1; t[b * ED + d2] = s2; }
    }
}

// Kernel 3 (fused, per-row): wave handles 16 rows; per row load k-row AND
// v-row, dot(k,t) -> shfl_xor butterfly -> w=exp(s/16) -> acc += w*v in
// registers. Best-measured variant (R5: 154 us @ ~3.45 TB/s read — the
// empirical per-chip read ceiling; R6's deeper pipeline/occupancy and R7's
// copy-shaped streams did not move it). grid (NCH, BB), block 256.
__global__ void k_fused(const float* __restrict__ k, const float* __restrict__ v,
                        const float* __restrict__ t, float* __restrict__ partial,
                        float* __restrict__ wsum) {
    int ch = blockIdx.x, b = blockIdx.y;
    int tid = threadIdx.x, wave = tid >> 6, lane = tid & 63;
    const float4* tb = (const float4*)(t + b * ED);
    float4 t0 = tb[lane], t1 = tb[64 + lane], t2 = tb[128 + lane], t3 = tb[192 + lane];
    int row0 = ch * KCH + wave * 16;
    const float4* kbase = (const float4*)(k + ((size_t)b * NK + row0) * ED);
    const float4* vbase = (const float4*)(v + ((size_t)b * NK + row0) * ED);
    float4 acc0 = {0,0,0,0}, acc1 = {0,0,0,0}, acc2 = {0,0,0,0}, acc3 = {0,0,0,0};
    float wacc = 0.f;
    #pragma unroll 2
    for (int r = 0; r < 16; ++r) {
        const float4* kr = kbase + (size_t)r * (ED / 4);
        const float4* vr = vbase + (size_t)r * (ED / 4);
        float4 k0 = kr[lane], k1 = kr[64 + lane], k2 = kr[128 + lane], k3 = kr[192 + lane];
        float4 v0 = vr[lane], v1 = vr[64 + lane], v2 = vr[128 + lane], v3 = vr[192 + lane];
        float s = k0.x*t0.x + k0.y*t0.y + k0.z*t0.z + k0.w*t0.w
                + k1.x*t1.x + k1.y*t1.y + k1.z*t1.z + k1.w*t1.w
                + k2.x*t2.x + k2.y*t2.y + k2.z*t2.z + k2.w*t2.w
                + k3.x*t3.x + k3.y*t3.y + k3.z*t3.z + k3.w*t3.w;
        #pragma unroll
        for (int m = 32; m; m >>= 1) s += __shfl_xor(s, m, 64);
        float w = __expf(s * 0.0625f);
        wacc += w;
        acc0.x += w*v0.x; acc0.y += w*v0.y; acc0.z += w*v0.z; acc0.w += w*v0.w;
        acc1.x += w*v1.x; acc1.y += w*v1.y; acc1.z += w*v1.z; acc1.w += w*v1.w;
        acc2.x += w*v2.x; acc2.y += w*v2.y; acc2.z += w*v2.z; acc2.w += w*v2.w;
        acc3.x += w*v3.x; acc3.y += w*v3.y; acc3.z += w*v3.z; acc3.w += w*v3.w;
    }
    __shared__ float4 red[4][256];   // 16 KB: [wave][float4-slot]
    red[wave][lane]       = acc0;
    red[wave][64 + lane]  = acc1;
    red[wave][128 + lane] = acc2;
    red[wave][192 + lane] = acc3;
    __shared__ float wred[4];
    if (lane == 0) wred[wave] = wacc;   // wacc uniform across lanes
    __syncthreads();
    float4 a0 = red[0][tid], a1 = red[1][tid], a2 = red[2][tid], a3 = red[3][tid];
    float4 r4;
    r4.x = a0.x + a1.x + a2.x + a3.x;
    r4.y = a0.y + a1.y + a2.y + a3.y;
    r4.z = a0.z + a1.z + a2.z + a3.z;
    r4.w = a0.w + a1.w + a2.w + a3.w;
    ((float4*)partial)[((size_t)(b * NCH + ch)) * (ED / 4) + tid] = r4;
    if (tid == 0) wsum[b * NCH + ch] = wred[0] + wred[1] + wred[2] + wred[3];
}

// Kernel 4: ov[b, dq*256..] = (sum_ch partial[b,ch,dq*256..]) / l[b].
// grid (16,4), block 256 = 4 ch-groups x 64 float4-cols.
__global__ void k_reduce(const float* __restrict__ partial, const float* __restrict__ wsum,
                         float* __restrict__ ov) {
    int b = blockIdx.x, dq = blockIdx.y, tid = threadIdx.x;
    int chg = tid >> 6, c = tid & 63;
    __shared__ float lsh;
    if (tid < 64) {
        float s = wsum[b * NCH + tid];
        #pragma unroll
        for (int off = 32; off; off >>= 1) s += __shfl_down(s, off, 64);
        if (tid == 0) lsh = s;
    }
    const float4* pb = (const float4*)(partial + (size_t)b * NCH * ED);
    float4 s4 = {0.f, 0.f, 0.f, 0.f};
    #pragma unroll 8
    for (int ch = chg; ch < NCH; ch += 4) {
        float4 p = pb[(size_t)ch * (ED / 4) + dq * 64 + c];
        s4.x += p.x; s4.y += p.y; s4.z += p.z; s4.w += p.w;
    }
    __shared__ float4 red[4][64];
    red[chg][c] = s4;
    __syncthreads();
    if (tid < 64) {
        float4 a0 = red[0][tid], a1 = red[1][tid], a2 = red[2][tid], a3 = red[3][tid];
        float linv = 1.0f / lsh;
        float4 r;
        r.x = (a0.x + a1.x + a2.x + a3.x) * linv;
        r.y = (a0.y + a1.y + a2.y + a3.y) * linv;
        r.z = (a0.z + a1.z + a2.z + a3.z) * linv;
        r.w = (a0.w + a1.w + a2.w + a3.w) * linv;
        ((float4*)(ov + b * ED + dq * 256))[tid] = r;
    }
}

// Kernel 5: out_part[dq][b][col] = sum_{d in quarter} ov[b,d]*Wv[d,col].
// grid (16 colblocks, 4 d-quarters), block 256 = 4 d-groups x 64 cols.
__global__ void k_out(const float* __restrict__ ov, const float* __restrict__ Wv,
                      float* __restrict__ opart) {
    int cb = blockIdx.x, dq = blockIdx.y, tid = threadIdx.x;
    int col = cb * 64 + (tid & 63), dg = tid >> 6;
    __shared__ float ovsh[BB][256];
    for (int i = tid; i < BB * 64; i += 256) {
        int bb = i >> 6, c4 = i & 63;
        ((float4*)ovsh[bb])[c4] = ((const float4*)(ov + bb * ED + dq * 256))[c4];
    }
    __syncthreads();
    float acc[BB];
    #pragma unroll
    for (int b = 0; b < BB; ++b) acc[b] = 0.f;
    #pragma unroll 8
    for (int it = 0; it < 64; ++it) {
        int dd = dg + it * 4;
        float w = Wv[(size_t)(dq * 256 + dd) * ED + col];
        #pragma unroll
        for (int b = 0; b < BB; ++b) acc[b] += ovsh[b][dd] * w;
    }
    __shared__ float red[BB][256];
    #pragma unroll
    for (int b = 0; b < BB; ++b) red[b][tid] = acc[b];
    __syncthreads();
    int bgrp = tid >> 6, c = tid & 63;
    #pragma unroll
    for (int bi = 0; bi < 4; ++bi) {
        int b = bgrp * 4 + bi;
        float s = red[b][c] + red[b][64 + c] + red[b][128 + c] + red[b][192 + c];
        opart[((size_t)(dq * BB + b)) * ED + cb * 64 + c] = s;
    }
}

// Kernel 6: out[b,:] = sum_dq out_part[dq][b][:] + bv. grid 16, block 256.
__global__ void k_final(const float* __restrict__ opart, const float* __restrict__ bv,
                        float* __restrict__ out) {
    int b = blockIdx.x, tid = threadIdx.x;
    float4 s = ((const float4*)(opart + (size_t)(0 * BB + b) * ED))[tid];
    #pragma unroll
    for (int dq = 1; dq < 4; ++dq) {
        float4 p = ((const float4*)(opart + (size_t)(dq * BB + b) * ED))[tid];
        s.x += p.x; s.y += p.y; s.z += p.z; s.w += p.w;
    }
    float4 bb = ((const float4*)bv)[tid];
    s.x += bb.x; s.y += bb.y; s.z += bb.z; s.w += bb.w;
    ((float4*)(out + b * ED))[tid] = s;
}

extern "C" void kernel_launch(void* const* d_in, const int* in_sizes, int n_in,
                              void* d_out, int out_size, void* d_ws, size_t ws_size,
                              hipStream_t stream) {
    const float* q   = (const float*)d_in[0];
    const float* k   = (const float*)d_in[1];
    const float* v   = (const float*)d_in[2];
    const float* Wkq = (const float*)d_in[3];
    const float* bkq = (const float*)d_in[4];
    const float* Wv  = (const float*)d_in[5];
    const float* bv  = (const float*)d_in[6];
    float* out = (float*)d_out;
    float* ws  = (float*)d_ws;

    float* qp      = ws + OFF_QP;
    float* t       = ws + OFF_T;
    float* wsum    = ws + OFF_WSUM;
    float* partial = ws + OFF_PART;
    float* ov      = ws + OFF_OV;
    float* opart   = ws + OFF_OPART;

    k_qp    <<<dim3(16, 4),   256, 0, stream>>>(q, Wkq, bkq, qp);
    k_t     <<<dim3(8, 16),   256, 0, stream>>>(Wkq, qp, t);
    k_fused <<<dim3(NCH, BB), 256, 0, stream>>>(k, v, t, partial, wsum);
    k_reduce<<<dim3(16, 4),   256, 0, stream>>>(partial, wsum, ov);
    k_out   <<<dim3(16, 4),   256, 0, stream>>>(ov, Wv, opart);
    k_final <<<16,            256, 0, stream>>>(opart, bv, out);
}